// Round 9
// baseline (335.788 us; speedup 1.0000x reference)
//
#include <hip/hip_runtime.h>
#include <hip/hip_bf16.h>
#include <math.h>

typedef __bf16 bf16x8 __attribute__((ext_vector_type(8)));
typedef __bf16 bf16x4 __attribute__((ext_vector_type(4)));
typedef unsigned short u16x8 __attribute__((ext_vector_type(8)));
typedef float f32x4 __attribute__((ext_vector_type(4)));

#define EP_QKV 0
#define EP_GELU 1
#define EP_RES 2

static __device__ __forceinline__ unsigned short f2bf(float x) {
  unsigned int u = __float_as_uint(x);
  unsigned int r = (u + 0x7fffu + ((u >> 16) & 1u)) >> 16;  // RNE
  return (unsigned short)r;
}

// pack two fp32 -> two bf16 (truncation) in ONE v_perm_b32
static __device__ __forceinline__ unsigned int pkbf(float lo, float hi) {
  return __builtin_amdgcn_perm(__float_as_uint(hi), __float_as_uint(lo), 0x07060302);
}

static __device__ __forceinline__ void async16(const void* g, void* l) {
  __builtin_amdgcn_global_load_lds((__attribute__((address_space(1))) void*)g,
                                   (__attribute__((address_space(3))) void*)l, 16, 0, 0);
}

// ---------------- weight convert + transpose: fp32 [K][N] -> bf16 [N][K] ----
__global__ __launch_bounds__(256) void wt_transpose(const float* __restrict__ in,
                                                    unsigned short* __restrict__ out,
                                                    int K, int N) {
  __shared__ float tile[32][33];
  const int n0 = blockIdx.x * 32;
  const int k0 = blockIdx.y * 32;
  const int tx = threadIdx.x;  // 0..31
  const int ty = threadIdx.y;  // 0..7
  #pragma unroll
  for (int i = ty; i < 32; i += 8)
    tile[i][tx] = in[(size_t)(k0 + i) * N + n0 + tx];
  __syncthreads();
  #pragma unroll
  for (int i = ty; i < 32; i += 8)
    out[(size_t)(n0 + i) * K + k0 + tx] = f2bf(tile[tx][i]);
}

// ---------------- layernorm fp32 -> bf16 -----------------------------------
__global__ __launch_bounds__(256) void ln_kernel(const float* __restrict__ x,
                                                 const float* __restrict__ g,
                                                 const float* __restrict__ b,
                                                 unsigned short* __restrict__ outp) {
  const int row = blockIdx.x;
  const int tid = threadIdx.x;
  const int wave = tid >> 6, lane = tid & 63;
  const float4 v = ((const float4*)(x + (size_t)row * 1024))[tid];
  float s = v.x + v.y + v.z + v.w;
  #pragma unroll
  for (int i = 1; i < 64; i <<= 1) s += __shfl_xor(s, i);
  __shared__ float red[4];
  if (lane == 0) red[wave] = s;
  __syncthreads();
  const float mean = (red[0] + red[1] + red[2] + red[3]) * (1.f / 1024.f);
  const float dx = v.x - mean, dy = v.y - mean, dz = v.z - mean, dw = v.w - mean;
  float ss = dx * dx + dy * dy + dz * dz + dw * dw;
  #pragma unroll
  for (int i = 1; i < 64; i <<= 1) ss += __shfl_xor(ss, i);
  __syncthreads();
  if (lane == 0) red[wave] = ss;
  __syncthreads();
  const float var = (red[0] + red[1] + red[2] + red[3]) * (1.f / 1024.f);
  const float inv = rsqrtf(var + 1e-6f);
  const float4 gv = ((const float4*)g)[tid];
  const float4 bv = ((const float4*)b)[tid];
  ushort4 o;
  o.x = f2bf(dx * inv * gv.x + bv.x);
  o.y = f2bf(dy * inv * gv.y + bv.y);
  o.z = f2bf(dz * inv * gv.z + bv.z);
  o.w = f2bf(dw * inv * gv.w + bv.w);
  ((ushort4*)(outp + (size_t)row * 1024))[tid] = o;
}

// ---------------- GEMM: C = A[M,K] * BT[N,K]^T + bias ----------------------
// Double-buffered software pipeline: barrier -> issue(t+1) -> compute(t).
// BK=64: compute phase ~ L2 latency, conflict-free 8-chunk xor swizzle.
// XCD-rectangle block swizzle: per-XCD L2 working set ~4-6 MB.
template <int TN, int BK>
__global__ __launch_bounds__(256) void gemm_kernel(
    const unsigned short* __restrict__ A,   // bf16 [M][K]
    const unsigned short* __restrict__ BT,  // bf16 [N][K]
    const float* __restrict__ bias,         // [N]
    int M, int N, int K, int mode,
    void* __restrict__ outp, const float* __restrict__ res) {
  constexpr int AM = (TN == 128) ? 4 : 2;   // m-subtiles per wave
  constexpr int ACH = BK / 16;              // A chunks per lane per stage
  constexpr int BCH = TN * BK / 2048;       // B chunks per lane per stage
  constexpr int CPR = BK / 8;               // 16B chunks per LDS row
  constexpr int ABYTES = 256 * BK;          // A stage bytes (128 rows)
  constexpr int BBYTES = TN * BK * 2;
  __shared__ __align__(16) char smem[2 * (ABYTES + BBYTES)];

  const int tid = threadIdx.x;
  const int wave = tid >> 6, lane = tid & 63;
  const int quad = lane >> 4, l16 = lane & 15;
  const int wm = (TN == 128) ? (wave >> 1) : wave;
  const int wn = (TN == 128) ? (wave & 1) : 0;

  // XCD-rectangle swizzle (requires nbm%4==0, nbn%2==0, grid%8==0)
  const int nbm = M >> 7, nbn = N / TN;
  const int lin = blockIdx.y * gridDim.x + blockIdx.x;
  const int g = lin & 7, idx = lin >> 3;
  const int gm = nbm >> 2, gn = nbn >> 1;
  const int bm = (g & 3) * gm + (idx % gm);
  const int bn = (g >> 2) * gn + (idx / gm);
  const int row_m = bm * 128, row_n = bn * TN;

  int ar[ACH], ac[ACH];
  #pragma unroll
  for (int i = 0; i < ACH; ++i) {
    const int c = wave * (64 * ACH) + i * 64 + lane;
    ar[i] = c / CPR;
    ac[i] = ((c % CPR) ^ (ar[i] & (CPR - 1))) * 8;
  }
  int br[BCH], bc[BCH];
  #pragma unroll
  for (int i = 0; i < BCH; ++i) {
    const int c = wave * (64 * BCH) + i * 64 + lane;
    br[i] = c / CPR;
    bc[i] = ((c % CPR) ^ (br[i] & (CPR - 1))) * 8;
  }

  const unsigned short* Ag = A + (size_t)row_m * K;
  const unsigned short* Bg = BT + (size_t)row_n * K;

  const f32x4 z = {0.f, 0.f, 0.f, 0.f};
  f32x4 acc[AM][4];
  #pragma unroll
  for (int i = 0; i < AM; ++i)
    #pragma unroll
    for (int j = 0; j < 4; ++j) acc[i][j] = z;

  auto issue = [&](int kt, int b) {
    unsigned short* As = (unsigned short*)(smem + b * ABYTES);
    unsigned short* Bs = (unsigned short*)(smem + 2 * ABYTES + b * BBYTES);
    #pragma unroll
    for (int i = 0; i < ACH; ++i)
      async16(Ag + (size_t)ar[i] * K + kt + ac[i], As + wave * (ACH * 512) + i * 512);
    #pragma unroll
    for (int i = 0; i < BCH; ++i)
      async16(Bg + (size_t)br[i] * K + kt + bc[i], Bs + wave * (BCH * 512) + i * 512);
  };

  issue(0, 0);
  for (int kt = 0; kt < K; kt += BK) {
    const int b = (kt / BK) & 1;
    __syncthreads();  // drains issue(kt) — issued a full compute-phase ago
    if (kt + BK < K) issue(kt + BK, b ^ 1);
    const unsigned short* As = (const unsigned short*)(smem + b * ABYTES);
    const unsigned short* Bs = (const unsigned short*)(smem + 2 * ABYTES + b * BBYTES);
    #pragma unroll
    for (int h = 0; h < BK / 32; ++h) {
      bf16x8 af[AM], bfv[4];
      #pragma unroll
      for (int t = 0; t < AM; ++t) {
        const int row = wm * (AM * 16) + t * 16 + l16;
        const int ch = (h * 4 + quad) ^ (row & (CPR - 1));
        af[t] = *(const bf16x8*)(As + row * BK + ch * 8);
      }
      #pragma unroll
      for (int t = 0; t < 4; ++t) {
        const int row = wn * 64 + t * 16 + l16;
        const int ch = (h * 4 + quad) ^ (row & (CPR - 1));
        bfv[t] = *(const bf16x8*)(Bs + row * BK + ch * 8);
      }
      #pragma unroll
      for (int tm = 0; tm < AM; ++tm)
        #pragma unroll
        for (int tn = 0; tn < 4; ++tn)
          acc[tm][tn] = __builtin_amdgcn_mfma_f32_16x16x32_bf16(af[tm], bfv[tn], acc[tm][tn], 0, 0, 0);
    }
  }

  // epilogue: C/D layout col = l16, row = quad*4 + reg
  #pragma unroll
  for (int tn = 0; tn < 4; ++tn) {
    const int col = row_n + wn * 64 + tn * 16 + l16;
    const float bv = bias[col];
    #pragma unroll
    for (int tm = 0; tm < AM; ++tm) {
      const int rbase = row_m + wm * (AM * 16) + tm * 16 + quad * 4;
      float v[4];
      #pragma unroll
      for (int r = 0; r < 4; ++r) v[r] = acc[tm][tn][r] + bv;
      if (mode == EP_QKV) {
        unsigned short* outw = (unsigned short*)outp;
        const int which = col >> 10;
        const int h = (col >> 6) & 15, d = col & 63;
        const int bb = rbase >> 11, n = rbase & 2047;
        const size_t bh = (size_t)(bb * 16 + h);
        if (which == 0) {
          // Q pre-scaled by 0.125*log2(e) so softmax is a bare v_exp_f32
          #pragma unroll
          for (int r = 0; r < 4; ++r)
            outw[(bh * 2048 + n + r) * 64 + d] = f2bf(v[r] * 0.18033688011112043f);
        } else if (which == 1) {
          #pragma unroll
          for (int r = 0; r < 4; ++r)
            outw[4194304ull + (bh * 2048 + n + r) * 64 + d] = f2bf(v[r]);
        } else {
          // VT with per-128 key interleave pi(n) so attention PV A-frags are
          // contiguous 16B chunks: pos = w*32 + q*8 + half*4 + r
          const int np = (n & ~127) | ((n & 0x3C) << 1) | ((n & 0x40) >> 4) | (n & 3);
          uint2 o;
          o.x = pkbf(v[0], v[1]);
          o.y = pkbf(v[2], v[3]);
          *(uint2*)(outw + 8388608ull + (bh * 64 + d) * 2048 + np) = o;
        }
      } else if (mode == EP_GELU) {
        #pragma unroll
        for (int r = 0; r < 4; ++r) {
          const float u = v[r];
          const float c = 1.5957691216f * fmaf(0.044715f * u * u, u, u);
          const float e = __expf(c);
          const float gl = u - __fdividef(u, e + 1.0f);
          ((unsigned short*)outp)[(size_t)(rbase + r) * N + col] = f2bf(gl);
        }
      } else {  // EP_RES
        #pragma unroll
        for (int r = 0; r < 4; ++r)
          ((float*)outp)[(size_t)(rbase + r) * N + col] =
              res[(size_t)(rbase + r) * N + col] + v[r];
      }
    }
  }
}

// ---------------- flash attention, key-split waves --------------------------
// p = v_exp(s') unshifted (constant factor cancels in O/l); l summed in the
// matrix pipe via ones-MFMA; V pre-interleaved so PV A-frags are single
// ds_read_b128.
__global__ __launch_bounds__(256) void attn_kernel(
    const unsigned short* __restrict__ Q,   // [BH][2048][64] (scaled .125*log2e)
    const unsigned short* __restrict__ Kb,  // [BH][2048][64]
    const unsigned short* __restrict__ VT,  // [BH][64][2048] key-interleaved
    unsigned short* __restrict__ outp) {    // [B*2048][1024]
  __shared__ __align__(16) char smem[73728];
  unsigned short* Qs = (unsigned short*)smem;            // [64][64]  swz8
  unsigned short* Ks = (unsigned short*)(smem + 8192);   // 2x [128][64] swz8
  unsigned short* Vs = (unsigned short*)(smem + 40960);  // 2x [64][128] swz16

  const int tid = threadIdx.x;
  const int wave = tid >> 6, lane = tid & 63;
  const int quad = lane >> 4, l16 = lane & 15;
  const int bhi = blockIdx.y;
  const int q0 = blockIdx.x * 64;

  const unsigned short* Qg = Q + ((size_t)bhi * 2048 + q0) * 64;
  const unsigned short* Kg = Kb + (size_t)bhi * 2048 * 64;
  const unsigned short* Vg = VT + (size_t)bhi * 64 * 2048;

  {
    const int c0 = wave * 128 + lane;
    const int r0 = c0 >> 3, k0 = ((c0 & 7) ^ (r0 & 7)) * 8;
    const int c1 = c0 + 64;
    const int r1 = c1 >> 3, k1 = ((c1 & 7) ^ (r1 & 7)) * 8;
    async16(Qg + r0 * 64 + k0, Qs + wave * 1024);
    async16(Qg + r1 * 64 + k1, Qs + wave * 1024 + 512);
  }

  const unsigned short* kp[4];
  const unsigned short* vp[4];
  #pragma unroll
  for (int i = 0; i < 4; ++i) {
    const int c = wave * 256 + i * 64 + lane;
    const int krr = c >> 3, kcc = ((c & 7) ^ (krr & 7)) * 8;
    const int vrr = c >> 4, vcc = ((c & 15) ^ (vrr & 15)) * 8;
    kp[i] = Kg + (size_t)krr * 64 + kcc;
    vp[i] = Vg + (size_t)vrr * 2048 + vcc;
  }

  auto issueKV = [&](int b) {
    unsigned short* Kd = Ks + b * 8192;
    unsigned short* Vd = Vs + b * 8192;
    #pragma unroll
    for (int i = 0; i < 4; ++i) async16(kp[i], Kd + wave * 2048 + i * 512);
    #pragma unroll
    for (int i = 0; i < 4; ++i) async16(vp[i], Vd + wave * 2048 + i * 512);
    #pragma unroll
    for (int i = 0; i < 4; ++i) { kp[i] += 8192; vp[i] += 128; }
  };

  issueKV(0);
  __syncthreads();  // drains Q + KV(0)

  bf16x8 qb[4][2];
  #pragma unroll
  for (int nt = 0; nt < 4; ++nt)
    #pragma unroll
    for (int h = 0; h < 2; ++h) {
      const int row = nt * 16 + l16;
      const int ch = (h * 4 + quad) ^ (row & 7);
      qb[nt][h] = *(const bf16x8*)(Qs + row * 64 + ch * 8);
    }

  bf16x8 ones;
  #pragma unroll
  for (int j = 0; j < 8; ++j) ones[j] = (__bf16)1.0f;

  const f32x4 z = {0.f, 0.f, 0.f, 0.f};
  f32x4 acc[4][4];
  f32x4 accl[4];
  #pragma unroll
  for (int i = 0; i < 4; ++i) {
    accl[i] = z;
    #pragma unroll
    for (int j = 0; j < 4; ++j) acc[i][j] = z;
  }

  const int rowA = wave * 16 + l16;
  const int rowB = 64 + rowA;
  const int swk = l16 & 7;

  auto compute = [&](int b) {
    const unsigned short* Ksb = Ks + b * 8192;
    const unsigned short* Vsb = Vs + b * 8192;
    f32x4 sA[4], sB[4];
    #pragma unroll
    for (int nt = 0; nt < 4; ++nt) { sA[nt] = z; sB[nt] = z; }
    #pragma unroll
    for (int h = 0; h < 2; ++h) {
      const int ch = (h * 4 + quad) ^ swk;
      bf16x8 kfA = *(const bf16x8*)(Ksb + rowA * 64 + ch * 8);
      bf16x8 kfB = *(const bf16x8*)(Ksb + rowB * 64 + ch * 8);
      #pragma unroll
      for (int nt = 0; nt < 4; ++nt) {
        sA[nt] = __builtin_amdgcn_mfma_f32_16x16x32_bf16(kfA, qb[nt][h], sA[nt], 0, 0, 0);
        sB[nt] = __builtin_amdgcn_mfma_f32_16x16x32_bf16(kfB, qb[nt][h], sB[nt], 0, 0, 0);
      }
    }
    // p = exp(s') — no shift; constant cancels in O/l. l via ones-MFMA.
    bf16x8 pb[4];
    #pragma unroll
    for (int nt = 0; nt < 4; ++nt) {
      union { unsigned int d[4]; bf16x8 b; } cv;
      cv.d[0] = pkbf(__builtin_amdgcn_exp2f(sA[nt][0]), __builtin_amdgcn_exp2f(sA[nt][1]));
      cv.d[1] = pkbf(__builtin_amdgcn_exp2f(sA[nt][2]), __builtin_amdgcn_exp2f(sA[nt][3]));
      cv.d[2] = pkbf(__builtin_amdgcn_exp2f(sB[nt][0]), __builtin_amdgcn_exp2f(sB[nt][1]));
      cv.d[3] = pkbf(__builtin_amdgcn_exp2f(sB[nt][2]), __builtin_amdgcn_exp2f(sB[nt][3]));
      pb[nt] = cv.b;
      accl[nt] = __builtin_amdgcn_mfma_f32_16x16x32_bf16(ones, pb[nt], accl[nt], 0, 0, 0);
    }
    #pragma unroll
    for (int mt = 0; mt < 4; ++mt) {
      const int d = mt * 16 + l16;
      bf16x8 vf = *(const bf16x8*)(Vsb + d * 128 + (((wave * 4 + quad) ^ (d & 15)) * 8));
      #pragma unroll
      for (int nt = 0; nt < 4; ++nt)
        acc[mt][nt] = __builtin_amdgcn_mfma_f32_16x16x32_bf16(vf, pb[nt], acc[mt][nt], 0, 0, 0);
    }
  };

  issueKV(1);
  compute(0);
  for (int t = 1; t < 16; ++t) {
    const int b = t & 1;
    __syncthreads();
    if (t + 1 < 16) issueKV(b ^ 1);
    compute(b);
  }
  __syncthreads();

  float* sc = (float*)smem;
  float* lred = (float*)(smem + 32768);
  // every quad holds the full wave-l (ones-MFMA rows identical); quad 0 writes
  if (quad == 0) {
    #pragma unroll
    for (int nt = 0; nt < 4; ++nt) lred[wave * 64 + nt * 16 + l16] = accl[nt][0];
  }
  if (wave >= 2) {
    float* dst = sc + (wave - 2) * 4096;
    #pragma unroll
    for (int mt = 0; mt < 4; ++mt)
      #pragma unroll
      for (int nt = 0; nt < 4; ++nt)
        *(f32x4*)(dst + (mt * 4 + nt) * 256 + lane * 4) = acc[mt][nt];
  }
  __syncthreads();
  if (wave < 2) {
    const float* src = sc + wave * 4096;
    #pragma unroll
    for (int mt = 0; mt < 4; ++mt)
      #pragma unroll
      for (int nt = 0; nt < 4; ++nt)
        acc[mt][nt] += *(const f32x4*)(src + (mt * 4 + nt) * 256 + lane * 4);
  }
  if (wave == 1) {
    float* dst = sc + 4096;
    #pragma unroll
    for (int mt = 0; mt < 4; ++mt)
      #pragma unroll
      for (int nt = 0; nt < 4; ++nt)
        *(f32x4*)(dst + (mt * 4 + nt) * 256 + lane * 4) = acc[mt][nt];
  }
  __syncthreads();
  if (wave == 0) {
    const float* src = sc + 4096;
    float linv[4];
    #pragma unroll
    for (int nt = 0; nt < 4; ++nt) {
      const int qi = nt * 16 + l16;
      const float l = lred[qi] + lred[64 + qi] + lred[128 + qi] + lred[192 + qi];
      linv[nt] = 1.0f / l;
    }
    const int b = bhi >> 4, h = bhi & 15;
    #pragma unroll
    for (int mt = 0; mt < 4; ++mt)
      #pragma unroll
      for (int nt = 0; nt < 4; ++nt) {
        f32x4 o = acc[mt][nt] + *(const f32x4*)(src + (mt * 4 + nt) * 256 + lane * 4);
        uint2 ov;
        ov.x = pkbf(o[0] * linv[nt], o[1] * linv[nt]);
        ov.y = pkbf(o[2] * linv[nt], o[3] * linv[nt]);
        *(uint2*)(outp + ((size_t)(b * 2048 + q0 + nt * 16 + l16)) * 1024 +
                  h * 64 + mt * 16 + quad * 4) = ov;
      }
  }
}

// ---------------- launch -----------------------------------------------------
extern "C" void kernel_launch(void* const* d_in, const int* in_sizes, int n_in,
                              void* d_out, int out_size, void* d_ws, size_t ws_size,
                              hipStream_t stream) {
  (void)in_sizes; (void)n_in; (void)out_size; (void)ws_size;
  const float* x      = (const float*)d_in[0];
  const float* ln1_g  = (const float*)d_in[1];
  const float* ln1_b  = (const float*)d_in[2];
  const float* w_qkv  = (const float*)d_in[3];
  const float* b_qkv  = (const float*)d_in[4];
  const float* w_proj = (const float*)d_in[5];
  const float* b_proj = (const float*)d_in[6];
  const float* ln2_g  = (const float*)d_in[7];
  const float* ln2_b  = (const float*)d_in[8];
  const float* w_fc1  = (const float*)d_in[9];
  const float* b_fc1  = (const float*)d_in[10];
  const float* w_fc2  = (const float*)d_in[11];
  const float* b_fc2  = (const float*)d_in[12];

  char* ws = (char*)d_ws;
  unsigned short* wqkvT  = (unsigned short*)(ws + 0);
  unsigned short* wprojT = (unsigned short*)(ws + 6291456);
  unsigned short* wfc1T  = (unsigned short*)(ws + 8388608);
  unsigned short* wfc2T  = (unsigned short*)(ws + 16777216);
  unsigned short* lnb    = (unsigned short*)(ws + 25165824);
  unsigned short* qkvb   = (unsigned short*)(ws + 33554432);
  unsigned short* attnb  = (unsigned short*)(ws + 58720256);
  float*          x2     = (float*)(ws + 67108864);
  unsigned short* hbuf   = qkvb;  // fc1 out aliases dead qkv region

  dim3 tb(32, 8);
  wt_transpose<<<dim3(96, 32), tb, 0, stream>>>(w_qkv, wqkvT, 1024, 3072);
  wt_transpose<<<dim3(32, 32), tb, 0, stream>>>(w_proj, wprojT, 1024, 1024);
  wt_transpose<<<dim3(128, 32), tb, 0, stream>>>(w_fc1, wfc1T, 1024, 4096);
  wt_transpose<<<dim3(32, 128), tb, 0, stream>>>(w_fc2, wfc2T, 4096, 1024);

  ln_kernel<<<4096, 256, 0, stream>>>(x, ln1_g, ln1_b, lnb);

  gemm_kernel<128, 64><<<dim3(24, 32), 256, 0, stream>>>(lnb, wqkvT, b_qkv, 4096, 3072, 1024,
                                                         EP_QKV, (void*)qkvb, nullptr);

  attn_kernel<<<dim3(32, 32), 256, 0, stream>>>(qkvb, qkvb + 4194304, qkvb + 8388608, attnb);

  gemm_kernel<64, 64><<<dim3(16, 32), 256, 0, stream>>>(attnb, wprojT, b_proj, 4096, 1024, 1024,
                                                        EP_RES, (void*)x2, x);

  ln_kernel<<<4096, 256, 0, stream>>>(x2, ln2_g, ln2_b, lnb);

  gemm_kernel<128, 64><<<dim3(32, 32), 256, 0, stream>>>(lnb, wfc1T, b_fc1, 4096, 4096, 1024,
                                                         EP_GELU, (void*)hbuf, nullptr);

  gemm_kernel<64, 64><<<dim3(16, 32), 256, 0, stream>>>(hbuf, wfc2T, b_fc2, 4096, 1024, 4096,
                                                        EP_RES, d_out, x2);
}